// Round 2
// baseline (1107.272 us; speedup 1.0000x reference)
//
#include <hip/hip_runtime.h>
#include <hip/hip_bf16.h>

// TTT-Linear fused pipeline. f32 in/out, bf16 internal compute via MFMA.
// Stages: cvt(f32->bf16) -> rope_tab -> GEMM1 (k,v proj + RoPE + head-transpose)
//         -> ttt_scan -> LayerNorm (in-place) -> GEMM2 (output proj -> d_out f32)

typedef __attribute__((ext_vector_type(4)))  float f32x4;
typedef __attribute__((ext_vector_type(16))) float f32x16;
typedef __attribute__((ext_vector_type(8)))  short s16x8;
typedef __attribute__((ext_vector_type(4)))  short s16x4;

#define B_   4
#define S_   4096
#define D_   2048
#define H_   16
#define DH_  128
#define MB_  16
#define NMB_ 256

__device__ __forceinline__ float b2f(short u){
  union { unsigned int i; float f; } x;
  x.i = ((unsigned int)(unsigned short)u) << 16;
  return x.f;
}
__device__ __forceinline__ short f2b(float f){
  __hip_bfloat16 h = __float2bfloat16(f);
  return *reinterpret_cast<short*>(&h);
}
__device__ __forceinline__ void gll16(const void* g, void* l){
  __builtin_amdgcn_global_load_lds(
      (const __attribute__((address_space(1))) unsigned int*)g,
      (__attribute__((address_space(3))) unsigned int*)l, 16, 0, 0);
}

// ---------------- f32 -> bf16 conversion --------------------------------------
__global__ __launch_bounds__(256) void cvt_kernel(
    const float* __restrict__ in, unsigned short* __restrict__ out, int n8)
{
  int i = blockIdx.x * 256 + threadIdx.x;
  if (i >= n8) return;
  const float4* p = (const float4*)in + (size_t)i * 2;
  float4 a = p[0], b = p[1];
  s16x8 o;
  o[0] = f2b(a.x); o[1] = f2b(a.y); o[2] = f2b(a.z); o[3] = f2b(a.w);
  o[4] = f2b(b.x); o[5] = f2b(b.y); o[6] = f2b(b.z); o[7] = f2b(b.w);
  *(s16x8*)&out[(size_t)i * 8] = o;
}

// ---------------- RoPE cos/sin table: tab[s*128 + i] = cos, [ +64+i] = sin ----
__global__ void rope_tab_kernel(float* __restrict__ tab){
  int idx = blockIdx.x * 256 + threadIdx.x;
  if (idx >= S_ * 64) return;
  int s = idx >> 6, i = idx & 63;
  double invf = pow(10000.0, -(double)(2 * i) / 128.0);
  double ang  = (double)s * invf;
  tab[s * 128 + i]      = (float)cos(ang);
  tab[s * 128 + 64 + i] = (float)sin(ang);
}

// ---------------- GEMM: C[128x128] = A-tile @ W-tile^T, epilogue fused --------
// MODE 0: A=xb, weights Wkb|Wvb (tile_n<16 -> k + RoPE -> k_scan; else v_scan)
// MODE 1: A=normalized ttt (bf16), weights Wob, write d_out (f32) row-major.
template<int MODE>
__global__ __launch_bounds__(256) void gemm_kernel(
    const unsigned short* __restrict__ A,
    const unsigned short* __restrict__ W0,
    const unsigned short* __restrict__ W1,
    const float* __restrict__ rope_tab,
    unsigned short* __restrict__ k_out,
    unsigned short* __restrict__ v_out,
    float* __restrict__ f_out)
{
  __shared__ __align__(16) char lds[36864];  // stage: A[0,16K)+B[16K,32K); epi: C [128][272B]
  const int tid = threadIdx.x;
  const int w = tid >> 6, l = tid & 63;
  const int bid = blockIdx.x;
  const int tile_m = bid & 127;
  const int tile_n = bid >> 7;

  const unsigned short* Wsel = W0;
  int nrow0 = tile_n * 128;
  if (MODE == 0 && tile_n >= 16){ Wsel = W1; nrow0 = (tile_n - 16) * 128; }

  // staging: q-th 16B chunk -> LDS linear; global source pre-swizzled (rule #21)
  size_t gA[4], gB[4]; int ldso[4];
  for (int i = 0; i < 4; ++i){
    int q   = tid + i * 256;
    int row = q >> 3;                                   // 8 chunks (128B) per row
    int cbl = ((q & 7) * 16) ^ ((row & 7) << 4);        // logical col-byte
    gA[i]   = (size_t)(tile_m * 128 + row) * (D_ * 2) + cbl;
    gB[i]   = (size_t)(nrow0 + row) * (D_ * 2) + cbl;
    ldso[i] = q * 16;
  }
  const char* Ab = (const char*)A;
  const char* Wb = (const char*)Wsel;

  f32x4 acc[4][4];
  for (int mi = 0; mi < 4; ++mi) for (int ni = 0; ni < 4; ++ni)
    acc[mi][ni] = (f32x4){0.f, 0.f, 0.f, 0.f};

  const int lr = l & 15, lk = l >> 4;
  const int m0 = (w >> 1) * 64, n0 = (w & 1) * 64;

  for (int kt = 0; kt < D_ / 64; ++kt){
    size_t ko = (size_t)kt * 128;
    #pragma unroll
    for (int i = 0; i < 4; ++i) gll16(Ab + gA[i] + ko, &lds[ldso[i]]);
    #pragma unroll
    for (int i = 0; i < 4; ++i) gll16(Wb + gB[i] + ko, &lds[16384 + ldso[i]]);
    __syncthreads();
    #pragma unroll
    for (int ks = 0; ks < 2; ++ks){
      s16x8 af[4], bfr[4];
      #pragma unroll
      for (int mi = 0; mi < 4; ++mi){
        int r = m0 + 16 * mi + lr;
        af[mi] = *(const s16x8*)&lds[r * 128 + ((64 * ks + 16 * lk) ^ ((r & 7) << 4))];
      }
      #pragma unroll
      for (int ni = 0; ni < 4; ++ni){
        int r = n0 + 16 * ni + lr;
        bfr[ni] = *(const s16x8*)&lds[16384 + r * 128 + ((64 * ks + 16 * lk) ^ ((r & 7) << 4))];
      }
      #pragma unroll
      for (int mi = 0; mi < 4; ++mi)
        #pragma unroll
        for (int ni = 0; ni < 4; ++ni)
          acc[mi][ni] = __builtin_amdgcn_mfma_f32_16x16x32_bf16(af[mi], bfr[ni], acc[mi][ni], 0, 0, 0);
    }
    __syncthreads();
  }

  if (MODE == 1){
    // direct f32 store from accumulators
    #pragma unroll
    for (int mi = 0; mi < 4; ++mi){
      #pragma unroll
      for (int ni = 0; ni < 4; ++ni){
        int col  = n0 + 16 * ni + lr;
        int rowb = m0 + 16 * mi + 4 * lk;
        size_t gbase = ((size_t)tile_m * 128 + rowb) * D_ + (size_t)tile_n * 128 + col;
        #pragma unroll
        for (int r = 0; r < 4; ++r)
          f_out[gbase + (size_t)r * D_] = acc[mi][ni][r];
      }
    }
    return;
  }

  // MODE 0 epilogue: acc -> C_lds (bf16, row pitch 272B = 16*17 to spread banks)
  #pragma unroll
  for (int mi = 0; mi < 4; ++mi){
    #pragma unroll
    for (int ni = 0; ni < 4; ++ni){
      int col  = n0 + 16 * ni + lr;
      int rowb = m0 + 16 * mi + 4 * lk;
      #pragma unroll
      for (int r = 0; r < 4; ++r)
        *(unsigned short*)&lds[(rowb + r) * 272 + col * 2] = (unsigned short)f2b(acc[mi][ni][r]);
    }
  }
  __syncthreads();

  const int r    = tid >> 1, half = tid & 1;
  const size_t grow = (size_t)tile_m * 128 + r;   // = b*S + s
  const int bb = (int)(grow >> 12);
  const int ss = (int)(grow & 4095);
  #pragma unroll
  for (int j = 0; j < 8; ++j){
    int c0 = half * 64 + 8 * j;
    s16x8 vals = *(const s16x8*)&lds[r * 272 + c0 * 2];
    if (tile_n >= 16){
      int h = tile_n - 16;
      *(s16x8*)&v_out[(((size_t)bb * H_ + h) * S_ + ss) * DH_ + c0] = vals;
    } else {
      int h = tile_n;
      s16x8 part = *(const s16x8*)&lds[r * 272 + (c0 ^ 64) * 2];  // rotate partner
      int i0 = c0 & 63;
      float sgn = half ? 1.0f : -1.0f;
      s16x8 o;
      #pragma unroll
      for (int e = 0; e < 8; ++e){
        float cs = rope_tab[ss * 128 + i0 + e];
        float sn = rope_tab[ss * 128 + 64 + i0 + e];
        o[e] = f2b(b2f(vals[e]) * cs + sgn * b2f(part[e]) * sn);
      }
      *(s16x8*)&k_out[(((size_t)bb * H_ + h) * S_ + ss) * DH_ + c0] = o;
    }
  }
}

// ---------------- TTT scan: 128 blocks = (b,h) x e-half; W f32 in registers ----
#define WT_OFF  0        // WT bf16 [64 e'][128 d], swizzled, 16384 B
#define KC_OFF  16384    // kc bf16 [16 s][128 d], swizzled, 4096 B
#define KCT_OFF 20480    // kcT bf16 [128 d][40], pitch 80B, cols 0..15 used, 10240 B
#define VCT_OFF 30720    // vcT bf16 [64 e'][20], pitch 40B, 2560 B
#define DT_OFF  33280    // diffT bf16 [64 e'][40], pitch 80B, 5120 B

__global__ __launch_bounds__(256) void ttt_scan(
    const unsigned short* __restrict__ k_scan,   // [B][H][S][128]
    const unsigned short* __restrict__ v_scan,
    unsigned short* __restrict__ ttt)            // [B][S][2048]
{
  __shared__ __align__(16) char lds[38400];
  const int tid = threadIdx.x, l = tid & 63, w = tid >> 6;
  const int blk = blockIdx.x, eh = blk & 1, bh = blk >> 1;
  const int h = bh & 15, b = bh >> 4;
  const int eb = eh * 64;
  const size_t kv_base = (size_t)bh * S_ * DH_;
  const float SCALE_NEG = -2.0f / (MB_ * DH_);   // -LR * inv_n

  // identity init of WT (bf16 shadow of W slice, transposed [e'][d], swizzled)
  for (int idx = tid; idx < 64 * 128; idx += 256){
    int e = idx >> 7, d = idx & 127;
    unsigned short val = (d == eb + e) ? (unsigned short)0x3F80 : (unsigned short)0;
    *(unsigned short*)&lds[WT_OFF + e * 256 + ((2 * d) ^ ((e & 7) << 4))] = val;
  }
  // f32 master W in registers: wave w owns d in [32w,32w+32), 32x32 frag layout
  const int lc = l & 31, lh5 = l >> 5;
  f32x16 Wf[2];
  #pragma unroll
  for (int n = 0; n < 2; ++n)
    #pragma unroll
    for (int rr = 0; rr < 16; ++rr){
      int d = 32 * w + (rr & 3) + 8 * (rr >> 2) + 4 * lh5;
      int e = 32 * n + lc;
      Wf[n][rr] = (d == eb + e) ? 1.0f : 0.0f;
    }

  const int srow = tid >> 4;          // 0..15 (s within chunk)
  const int sc16 = tid & 15;
  s16x8 kreg = *(const s16x8*)&k_scan[kv_base + srow * 128 + sc16 * 8];
  s16x4 vreg = *(const s16x4*)&v_scan[kv_base + srow * 128 + eb + sc16 * 4];

  const int lr = l & 15, lk = l >> 4;

  for (int c = 0; c < NMB_; ++c){
    // stage regs -> LDS (kc swizzled b128; kcT / vcT scalar transposes, j-rotated)
    *(s16x8*)&lds[KC_OFF + srow * 256 + ((sc16 * 16) ^ ((srow & 7) << 4))] = kreg;
    #pragma unroll
    for (int j = 0; j < 8; ++j){
      int jp = (j + sc16) & 7;
      *(unsigned short*)&lds[KCT_OFF + (sc16 * 8 + jp) * 80 + srow * 2] = (unsigned short)kreg[jp];
    }
    #pragma unroll
    for (int j = 0; j < 4; ++j){
      int jp = (j + sc16) & 3;
      *(unsigned short*)&lds[VCT_OFF + (sc16 * 4 + jp) * 40 + srow * 2] = (unsigned short)vreg[jp];
    }
    // prefetch next chunk (latency hidden under z+grad phases)
    if (c + 1 < NMB_){
      size_t nb = kv_base + (size_t)(c + 1) * (MB_ * DH_);
      kreg = *(const s16x8*)&k_scan[nb + srow * 128 + sc16 * 8];
      vreg = *(const s16x4*)&v_scan[nb + srow * 128 + eb + sc16 * 4];
    }
    __syncthreads();

    // z = kc @ W   (wave w -> e' tile [16w,16w+16))
    f32x4 z = (f32x4){0.f, 0.f, 0.f, 0.f};
    const int ep = 16 * w + lr;
    #pragma unroll
    for (int ks = 0; ks < 4; ++ks){
      s16x8 a  = *(const s16x8*)&lds[KC_OFF + lr * 256 + ((64 * ks + 16 * lk) ^ ((lr & 7) << 4))];
      s16x8 bb2 = *(const s16x8*)&lds[WT_OFF + ep * 256 + ((64 * ks + 16 * lk) ^ ((ep & 7) << 4))];
      z = __builtin_amdgcn_mfma_f32_16x16x32_bf16(a, bb2, z, 0, 0, 0);
    }
    // diff, z writeout (bf16 into ttt), diffT (pre-scaled by -LR*inv_n)
    {
      const int s0 = 4 * lk;
      s16x4 vv = *(const s16x4*)&lds[VCT_OFF + ep * 40 + s0 * 2];
      s16x4 dpack;
      size_t orow = ((size_t)b * S_ + c * MB_ + s0) * D_ + h * DH_ + eb + ep;
      #pragma unroll
      for (int rr = 0; rr < 4; ++rr){
        float zv = z[rr];
        ttt[orow + (size_t)rr * D_] = (unsigned short)f2b(zv);
        dpack[rr] = f2b((zv - b2f(vv[rr])) * SCALE_NEG);
      }
      *(s16x4*)&lds[DT_OFF + ep * 80 + s0 * 2] = dpack;
    }
    __syncthreads();

    // W += kcT @ diffT  (one 32x32x16 MFMA per n-half, C-accum = W registers)
    {
      s16x8 a = *(const s16x8*)&lds[KCT_OFF + (32 * w + lc) * 80 + 16 * lh5];
      #pragma unroll
      for (int n = 0; n < 2; ++n){
        s16x8 bb2 = *(const s16x8*)&lds[DT_OFF + (32 * n + lc) * 80 + 16 * lh5];
        Wf[n] = __builtin_amdgcn_mfma_f32_32x32x16_bf16(a, bb2, Wf[n], 0, 0, 0);
      }
      // refresh bf16 shadow
      #pragma unroll
      for (int n = 0; n < 2; ++n){
        int e = 32 * n + lc;
        #pragma unroll
        for (int g = 0; g < 4; ++g){
          int d0 = 32 * w + 8 * g + 4 * lh5;
          s16x4 p;
          #pragma unroll
          for (int rr = 0; rr < 4; ++rr) p[rr] = f2b(Wf[n][4 * g + rr]);
          *(s16x4*)&lds[WT_OFF + e * 256 + ((2 * d0) ^ ((e & 7) << 4))] = p;
        }
      }
    }
    __syncthreads();
  }
}

// ---------------- row LayerNorm, in place (bf16 io, f32 gamma/beta) -----------
__global__ __launch_bounds__(256) void ln_kernel(
    unsigned short* __restrict__ io,
    const float* __restrict__ gamma,
    const float* __restrict__ beta)
{
  const int row = blockIdx.x, tid = threadIdx.x;
  const size_t base = (size_t)row * D_ + tid * 8;
  s16x8 v = *(const s16x8*)&io[base];
  float f[8], s1 = 0.f, s2 = 0.f;
  #pragma unroll
  for (int j = 0; j < 8; ++j){ f[j] = b2f(v[j]); s1 += f[j]; s2 += f[j] * f[j]; }
  #pragma unroll
  for (int off = 32; off; off >>= 1){
    s1 += __shfl_xor(s1, off);
    s2 += __shfl_xor(s2, off);
  }
  __shared__ float red[8];
  const int w = tid >> 6, l = tid & 63;
  if (l == 0){ red[w] = s1; red[4 + w] = s2; }
  __syncthreads();
  s1 = red[0] + red[1] + red[2] + red[3];
  s2 = red[4] + red[5] + red[6] + red[7];
  const float mu  = s1 * (1.0f / D_);
  const float var = s2 * (1.0f / D_) - mu * mu;
  const float rs  = rsqrtf(var + 1e-5f);
  const float4* gp = (const float4*)&gamma[tid * 8];
  const float4* bp = (const float4*)&beta[tid * 8];
  float4 g0 = gp[0], g1 = gp[1], b0 = bp[0], b1 = bp[1];
  float gg[8] = {g0.x,g0.y,g0.z,g0.w,g1.x,g1.y,g1.z,g1.w};
  float bb[8] = {b0.x,b0.y,b0.z,b0.w,b1.x,b1.y,b1.z,b1.w};
  s16x8 o;
  #pragma unroll
  for (int j = 0; j < 8; ++j)
    o[j] = f2b((f[j] - mu) * rs * gg[j] + bb[j]);
  *(s16x8*)&io[base] = o;
}

// ---------------- launch ------------------------------------------------------
extern "C" void kernel_launch(void* const* d_in, const int* in_sizes, int n_in,
                              void* d_out, int out_size, void* d_ws, size_t ws_size,
                              hipStream_t stream)
{
  const float* x     = (const float*)d_in[0];
  const float* Wk    = (const float*)d_in[1];
  const float* Wv    = (const float*)d_in[2];
  const float* Wo    = (const float*)d_in[3];
  const float* gamma = (const float*)d_in[4];
  const float* beta  = (const float*)d_in[5];
  float* out = (float*)d_out;

  // workspace layout (bytes):
  //  rope_tab 2MB | xb/ttt 64MB | k_scan 64MB | v_scan 64MB | Wkb 8MB | Wvb 8MB | Wob 8MB
  char* ws = (char*)d_ws;
  float* rope_tab        = (float*)ws;
  unsigned short* xb     = (unsigned short*)(ws + (2u << 20));
  unsigned short* k_scan = (unsigned short*)(ws + (2u << 20) + 1 * 67108864ull);
  unsigned short* v_scan = (unsigned short*)(ws + (2u << 20) + 2 * 67108864ull);
  unsigned short* Wkb    = (unsigned short*)(ws + (2u << 20) + 3 * 67108864ull);
  unsigned short* Wvb    = (unsigned short*)(ws + (2u << 20) + 3 * 67108864ull + 1 * 8388608ull);
  unsigned short* Wob    = (unsigned short*)(ws + (2u << 20) + 3 * 67108864ull + 2 * 8388608ull);
  unsigned short* ttt    = xb;  // x dead after GEMM1

  const int nx8 = B_ * S_ * D_ / 8;        // 4,194,304
  const int nw8 = D_ * D_ / 8;             // 524,288
  cvt_kernel<<<dim3(nx8 / 256), dim3(256), 0, stream>>>(x,  xb,  nx8);
  cvt_kernel<<<dim3(nw8 / 256), dim3(256), 0, stream>>>(Wk, Wkb, nw8);
  cvt_kernel<<<dim3(nw8 / 256), dim3(256), 0, stream>>>(Wv, Wvb, nw8);
  cvt_kernel<<<dim3(nw8 / 256), dim3(256), 0, stream>>>(Wo, Wob, nw8);
  rope_tab_kernel<<<dim3(1024), dim3(256), 0, stream>>>(rope_tab);

  gemm_kernel<0><<<dim3(128 * 32), dim3(256), 0, stream>>>(
      xb, Wkb, Wvb, rope_tab, k_scan, v_scan, nullptr);
  ttt_scan<<<dim3(128), dim3(256), 0, stream>>>(k_scan, v_scan, ttt);
  ln_kernel<<<dim3(B_ * S_), dim3(256), 0, stream>>>(ttt, gamma, beta);
  gemm_kernel<1><<<dim3(128 * 16), dim3(256), 0, stream>>>(
      ttt, Wob, nullptr, nullptr, nullptr, nullptr, out);
}

// Round 3
// 1078.882 us; speedup vs baseline: 1.0263x; 1.0263x over previous
//
#include <hip/hip_runtime.h>
#include <hip/hip_bf16.h>

// TTT-Linear fused pipeline. f32 in/out, bf16 internal compute via MFMA.
// Stages: cvt(f32->bf16) -> rope_tab -> gemm_kv (k,v proj + RoPE + head-transpose)
//         -> ttt_scan -> LayerNorm (in-place) -> gemm_out (output proj -> d_out f32)

typedef __attribute__((ext_vector_type(4)))  float f32x4;
typedef __attribute__((ext_vector_type(16))) float f32x16;
typedef __attribute__((ext_vector_type(8)))  short s16x8;
typedef __attribute__((ext_vector_type(4)))  short s16x4;

#define B_   4
#define S_   4096
#define D_   2048
#define H_   16
#define DH_  128
#define MB_  16
#define NMB_ 256

__device__ __forceinline__ float b2f(short u){
  union { unsigned int i; float f; } x;
  x.i = ((unsigned int)(unsigned short)u) << 16;
  return x.f;
}
__device__ __forceinline__ short f2b(float f){
  __hip_bfloat16 h = __float2bfloat16(f);
  return *reinterpret_cast<short*>(&h);
}
__device__ __forceinline__ void gll16(const void* g, void* l){
  __builtin_amdgcn_global_load_lds(
      (const __attribute__((address_space(1))) unsigned int*)g,
      (__attribute__((address_space(3))) unsigned int*)l, 16, 0, 0);
}

// ---------------- f32 -> bf16 conversion --------------------------------------
__global__ __launch_bounds__(256) void cvt_kernel(
    const float* __restrict__ in, unsigned short* __restrict__ out, int n8)
{
  int i = blockIdx.x * 256 + threadIdx.x;
  if (i >= n8) return;
  const float4* p = (const float4*)in + (size_t)i * 2;
  float4 a = p[0], b = p[1];
  s16x8 o;
  o[0] = f2b(a.x); o[1] = f2b(a.y); o[2] = f2b(a.z); o[3] = f2b(a.w);
  o[4] = f2b(b.x); o[5] = f2b(b.y); o[6] = f2b(b.z); o[7] = f2b(b.w);
  *(s16x8*)&out[(size_t)i * 8] = o;
}

// weights: 3 regions of D_*D_/8 vec8 chunks each
__global__ __launch_bounds__(256) void cvt3_kernel(
    const float* __restrict__ w0, const float* __restrict__ w1, const float* __restrict__ w2,
    unsigned short* __restrict__ o0, unsigned short* __restrict__ o1, unsigned short* __restrict__ o2)
{
  const int per = D_ * D_ / 8;               // 524288 chunks -> 2048 blocks each
  int i = blockIdx.x * 256 + threadIdx.x;
  const float* in; unsigned short* out;
  if (i < per)            { in = w0; out = o0; }
  else if (i < 2 * per)   { in = w1; out = o1; i -= per; }
  else                    { in = w2; out = o2; i -= 2 * per; }
  const float4* p = (const float4*)in + (size_t)i * 2;
  float4 a = p[0], b = p[1];
  s16x8 o;
  o[0] = f2b(a.x); o[1] = f2b(a.y); o[2] = f2b(a.z); o[3] = f2b(a.w);
  o[4] = f2b(b.x); o[5] = f2b(b.y); o[6] = f2b(b.z); o[7] = f2b(b.w);
  *(s16x8*)&out[(size_t)i * 8] = o;
}

// ---------------- RoPE cos/sin table: tab[s*128 + i] = cos, [ +64+i] = sin ----
__global__ void rope_tab_kernel(float* __restrict__ tab){
  int idx = blockIdx.x * 256 + threadIdx.x;
  if (idx >= S_ * 64) return;
  int s = idx >> 6, i = idx & 63;
  double invf = pow(10000.0, -(double)(2 * i) / 128.0);
  double ang  = (double)s * invf;
  tab[s * 128 + i]      = (float)cos(ang);
  tab[s * 128 + 64 + i] = (float)sin(ang);
}

// ---------------- shared 128x128-tile mainloop (BK=64, st-swizzled LDS) -------
__device__ __forceinline__ void mainloop_128(
    const char* __restrict__ Ab, const char* __restrict__ Wb,
    char* lds, int tid, f32x4 (&acc)[4][4])
{
  const int w = tid >> 6, l = tid & 63;
  const int lr = l & 15, lk = l >> 4;
  const int m0 = (w >> 1) * 64, n0 = (w & 1) * 64;

  size_t g[4]; int ldso[4];
  #pragma unroll
  for (int i = 0; i < 4; ++i){
    int q   = tid + i * 256;
    int row = q >> 3;                                   // 8 chunks (128B) per row
    int cbl = ((q & 7) * 16) ^ ((row & 7) << 4);        // pre-swizzled source col
    g[i]    = (size_t)row * (D_ * 2) + cbl;
    ldso[i] = q * 16;
  }

  for (int kt = 0; kt < D_ / 64; ++kt){
    size_t ko = (size_t)kt * 128;
    #pragma unroll
    for (int i = 0; i < 4; ++i) gll16(Ab + g[i] + ko, &lds[ldso[i]]);
    #pragma unroll
    for (int i = 0; i < 4; ++i) gll16(Wb + g[i] + ko, &lds[16384 + ldso[i]]);
    __syncthreads();
    #pragma unroll
    for (int ks = 0; ks < 2; ++ks){
      s16x8 af[4], bfr[4];
      #pragma unroll
      for (int mi = 0; mi < 4; ++mi){
        int r = m0 + 16 * mi + lr;
        af[mi] = *(const s16x8*)&lds[r * 128 + ((64 * ks + 16 * lk) ^ ((r & 7) << 4))];
      }
      #pragma unroll
      for (int ni = 0; ni < 4; ++ni){
        int r = n0 + 16 * ni + lr;
        bfr[ni] = *(const s16x8*)&lds[16384 + r * 128 + ((64 * ks + 16 * lk) ^ ((r & 7) << 4))];
      }
      #pragma unroll
      for (int mi = 0; mi < 4; ++mi)
        #pragma unroll
        for (int ni = 0; ni < 4; ++ni)
          acc[mi][ni] = __builtin_amdgcn_mfma_f32_16x16x32_bf16(af[mi], bfr[ni], acc[mi][ni], 0, 0, 0);
    }
    __syncthreads();
  }
}

// ---------------- GEMM1: k,v projections + RoPE + head-transpose --------------
// grid 4096: XCD-chunked: tile_n = (bid&7)*4 + (local&3), tile_m = local>>2
__global__ __launch_bounds__(256) void gemm_kv(
    const unsigned short* __restrict__ A,
    const unsigned short* __restrict__ W0,
    const unsigned short* __restrict__ W1,
    const float* __restrict__ rope_tab,
    unsigned short* __restrict__ k_out,
    unsigned short* __restrict__ v_out)
{
  __shared__ __align__(16) char lds[36864];
  const int tid = threadIdx.x;
  const int bid = blockIdx.x;
  const int local  = bid >> 3;
  const int tile_n = (bid & 7) * 4 + (local & 3);
  const int tile_m = local >> 2;

  const unsigned short* Wsel = (tile_n >= 16) ? W1 : W0;
  const int nrow0 = (tile_n >= 16) ? (tile_n - 16) * 128 : tile_n * 128;

  f32x4 acc[4][4];
  for (int mi = 0; mi < 4; ++mi) for (int ni = 0; ni < 4; ++ni)
    acc[mi][ni] = (f32x4){0.f, 0.f, 0.f, 0.f};

  mainloop_128((const char*)A + (size_t)tile_m * 128 * (D_ * 2),
               (const char*)Wsel + (size_t)nrow0 * (D_ * 2), lds, tid, acc);

  const int w = tid >> 6, l = tid & 63;
  const int lr = l & 15, lk = l >> 4;
  const int m0 = (w >> 1) * 64, n0 = (w & 1) * 64;

  // acc -> C_lds bf16, row pitch 272B
  #pragma unroll
  for (int mi = 0; mi < 4; ++mi){
    #pragma unroll
    for (int ni = 0; ni < 4; ++ni){
      int col  = n0 + 16 * ni + lr;
      int rowb = m0 + 16 * mi + 4 * lk;
      #pragma unroll
      for (int r = 0; r < 4; ++r)
        *(unsigned short*)&lds[(rowb + r) * 272 + col * 2] = (unsigned short)f2b(acc[mi][ni][r]);
    }
  }
  __syncthreads();

  const int r    = tid >> 1, half = tid & 1;
  const size_t grow = (size_t)tile_m * 128 + r;   // = b*S + s
  const int bb = (int)(grow >> 12);
  const int ss = (int)(grow & 4095);
  #pragma unroll
  for (int j = 0; j < 8; ++j){
    int c0 = half * 64 + 8 * j;
    s16x8 vals = *(const s16x8*)&lds[r * 272 + c0 * 2];
    if (tile_n >= 16){
      int h = tile_n - 16;
      *(s16x8*)&v_out[(((size_t)bb * H_ + h) * S_ + ss) * DH_ + c0] = vals;
    } else {
      int h = tile_n;
      s16x8 part = *(const s16x8*)&lds[r * 272 + (c0 ^ 64) * 2];  // rotate partner
      int i0 = c0 & 63;
      float sgn = half ? 1.0f : -1.0f;
      s16x8 o;
      #pragma unroll
      for (int e = 0; e < 8; ++e){
        float cs = rope_tab[ss * 128 + i0 + e];
        float sn = rope_tab[ss * 128 + 64 + i0 + e];
        o[e] = f2b(b2f(vals[e]) * cs + sgn * b2f(part[e]) * sn);
      }
      *(s16x8*)&k_out[(((size_t)bb * H_ + h) * S_ + ss) * DH_ + c0] = o;
    }
  }
}

// ---------------- GEMM2: output projection, f32 coalesced stores --------------
// grid 2048: tile_n = (bid&7)*2 + (local&1), tile_m = local>>1
__global__ __launch_bounds__(256) void gemm_out(
    const unsigned short* __restrict__ A,
    const unsigned short* __restrict__ W0,
    float* __restrict__ f_out)
{
  __shared__ __align__(16) char lds[36864];
  const int tid = threadIdx.x;
  const int bid = blockIdx.x;
  const int local  = bid >> 3;
  const int tile_n = (bid & 7) * 2 + (local & 1);
  const int tile_m = local >> 1;

  f32x4 acc[4][4];
  for (int mi = 0; mi < 4; ++mi) for (int ni = 0; ni < 4; ++ni)
    acc[mi][ni] = (f32x4){0.f, 0.f, 0.f, 0.f};

  mainloop_128((const char*)A + (size_t)tile_m * 128 * (D_ * 2),
               (const char*)W0 + (size_t)tile_n * 128 * (D_ * 2), lds, tid, acc);

  const int w = tid >> 6, l = tid & 63;
  const int lr = l & 15, lk = l >> 4;
  const int n0 = (w & 1) * 64;
  const int mh_own = w >> 1;            // which m-half this wave's acc covers
  float* lf = (float*)lds;              // [64][132] f32 = 33792 B

  #pragma unroll
  for (int mh = 0; mh < 2; ++mh){
    __syncthreads();
    if (mh_own == mh){
      #pragma unroll
      for (int mi = 0; mi < 4; ++mi){
        #pragma unroll
        for (int ni = 0; ni < 4; ++ni){
          int col = n0 + 16 * ni + lr;
          int rowl = 16 * mi + 4 * lk;
          #pragma unroll
          for (int r = 0; r < 4; ++r)
            lf[(rowl + r) * 132 + col] = acc[mi][ni][r];
        }
      }
    }
    __syncthreads();
    #pragma unroll
    for (int j2 = 0; j2 < 8; ++j2){
      int idx = tid + 256 * j2;         // 0..2047
      int row = idx >> 5, c4 = idx & 31;
      f32x4 vv = *(const f32x4*)&lf[row * 132 + c4 * 4];
      size_t grow = (size_t)tile_m * 128 + mh * 64 + row;
      *(f32x4*)&f_out[grow * D_ + (size_t)tile_n * 128 + c4 * 4] = vv;
    }
  }
}

// ---------------- TTT scan: 128 blocks = (b,h) x e-half; W f32 in registers ----
// LDS layout (bytes):
#define WT_OFF  0        // WT bf16 [64 e'][128 d], swizzled, 16384
#define KC_OFF  16384    // kc bf16 x2 buf [16 s][128 d] swizzled, 4096 each
#define KCT_OFF 24576    // kcT bf16 x2 buf [128 d][pitch 88B], 11264 each
#define VCT_OFF 47104    // vcT bf16 x2 buf [64 e'][pitch 40B], 2560 each
#define DT_OFF  52224    // diffT bf16 [64 e'][pitch 88B], 5632
// total 57856

__device__ __forceinline__ void stage_chunk(char* lds, int buf, int srow, int sc16,
                                            const s16x8& kreg, const s16x4& vreg)
{
  char* kc  = lds + KC_OFF  + buf * 4096;
  char* kct = lds + KCT_OFF + buf * 11264;
  char* vct = lds + VCT_OFF + buf * 2560;
  *(s16x8*)&kc[srow * 256 + ((sc16 * 16) ^ ((srow & 7) << 4))] = kreg;
  #pragma unroll
  for (int j = 0; j < 8; ++j){
    int jp = (j + sc16) & 7;
    *(unsigned short*)&kct[(sc16 * 8 + jp) * 88 + srow * 2] = (unsigned short)kreg[jp];
  }
  #pragma unroll
  for (int j = 0; j < 4; ++j){
    int jp = (j + sc16) & 3;
    *(unsigned short*)&vct[(sc16 * 4 + jp) * 40 + srow * 2] = (unsigned short)vreg[jp];
  }
}

__global__ __launch_bounds__(256) void ttt_scan(
    const unsigned short* __restrict__ k_scan,   // [B][H][S][128]
    const unsigned short* __restrict__ v_scan,
    unsigned short* __restrict__ ttt)            // [B][S][2048]
{
  __shared__ __align__(16) char lds[57856];
  const int tid = threadIdx.x, l = tid & 63, w = tid >> 6;
  const int blk = blockIdx.x, eh = blk & 1, bh = blk >> 1;
  const int h = bh & 15, b = bh >> 4;
  const int eb = eh * 64;
  const size_t kv_base = (size_t)bh * S_ * DH_;
  const float SCALE_NEG = -2.0f / (MB_ * DH_);   // -LR * inv_n

  // identity init of WT (bf16 shadow, transposed [e'][d], swizzled)
  for (int idx = tid; idx < 64 * 128; idx += 256){
    int e = idx >> 7, d = idx & 127;
    unsigned short val = (d == eb + e) ? (unsigned short)0x3F80 : (unsigned short)0;
    *(unsigned short*)&lds[WT_OFF + e * 256 + ((2 * d) ^ ((e & 7) << 4))] = val;
  }
  // f32 master W in registers (32x32 C-frag layout), wave w owns d in [32w,32w+32)
  const int lc = l & 31, lh5 = l >> 5;
  f32x16 Wf[2];
  #pragma unroll
  for (int n = 0; n < 2; ++n)
    #pragma unroll
    for (int rr = 0; rr < 16; ++rr){
      int d = 32 * w + (rr & 3) + 8 * (rr >> 2) + 4 * lh5;
      int e = 32 * n + lc;
      Wf[n][rr] = (d == eb + e) ? 1.0f : 0.0f;
    }

  const int srow = tid >> 4;          // s within chunk
  const int sc16 = tid & 15;
  s16x8 kreg = *(const s16x8*)&k_scan[kv_base + srow * 128 + sc16 * 8];
  s16x4 vreg = *(const s16x4*)&v_scan[kv_base + srow * 128 + eb + sc16 * 4];
  stage_chunk(lds, 0, srow, sc16, kreg, vreg);
  {
    size_t nb = kv_base + (size_t)(MB_ * DH_);
    kreg = *(const s16x8*)&k_scan[nb + srow * 128 + sc16 * 8];
    vreg = *(const s16x4*)&v_scan[nb + srow * 128 + eb + sc16 * 4];
  }
  __syncthreads();

  const int lr = l & 15, lk = l >> 4;

  for (int c = 0; c < NMB_; ++c){
    const int cur = c & 1;
    // -------- phase A: stage c+1, prefetch c+2, z-mfma, diff --------
    if (c + 1 < NMB_) stage_chunk(lds, cur ^ 1, srow, sc16, kreg, vreg);
    if (c + 2 < NMB_){
      size_t nb = kv_base + (size_t)(c + 2) * (MB_ * DH_);
      kreg = *(const s16x8*)&k_scan[nb + srow * 128 + sc16 * 8];
      vreg = *(const s16x4*)&v_scan[nb + srow * 128 + eb + sc16 * 4];
    }

    const char* kc = lds + KC_OFF + cur * 4096;
    f32x4 z = (f32x4){0.f, 0.f, 0.f, 0.f};
    const int ep = 16 * w + lr;
    #pragma unroll
    for (int ks = 0; ks < 4; ++ks){
      s16x8 a   = *(const s16x8*)&kc[lr * 256 + ((64 * ks + 16 * lk) ^ ((lr & 7) << 4))];
      s16x8 bb2 = *(const s16x8*)&lds[WT_OFF + ep * 256 + ((64 * ks + 16 * lk) ^ ((ep & 7) << 4))];
      z = __builtin_amdgcn_mfma_f32_16x16x32_bf16(a, bb2, z, 0, 0, 0);
    }
    {
      const char* vct = lds + VCT_OFF + cur * 2560;
      const int s0 = 4 * lk;
      s16x4 vv = *(const s16x4*)&vct[ep * 40 + s0 * 2];
      s16x4 dpack;
      size_t orow = ((size_t)b * S_ + c * MB_ + s0) * D_ + h * DH_ + eb + ep;
      #pragma unroll
      for (int rr = 0; rr < 4; ++rr){
        float zv = z[rr];
        ttt[orow + (size_t)rr * D_] = (unsigned short)f2b(zv);
        dpack[rr] = f2b((zv - b2f(vv[rr])) * SCALE_NEG);
      }
      *(s16x4*)&lds[DT_OFF + ep * 88 + s0 * 2] = dpack;
    }
    __syncthreads();

    // -------- phase B: W += kcT @ diffT; refresh bf16 shadow --------
    {
      const char* kct = lds + KCT_OFF + cur * 11264;
      s16x8 a = *(const s16x8*)&kct[(32 * w + lc) * 88 + 16 * lh5];
      #pragma unroll
      for (int n = 0; n < 2; ++n){
        s16x8 bb2 = *(const s16x8*)&lds[DT_OFF + (32 * n + lc) * 88 + 16 * lh5];
        Wf[n] = __builtin_amdgcn_mfma_f32_32x32x16_bf16(a, bb2, Wf[n], 0, 0, 0);
      }
      #pragma unroll
      for (int n = 0; n < 2; ++n){
        int e = 32 * n + lc;
        #pragma unroll
        for (int g = 0; g < 4; ++g){
          int d0 = 32 * w + 8 * g + 4 * lh5;
          s16x4 p;
          #pragma unroll
          for (int rr = 0; rr < 4; ++rr) p[rr] = f2b(Wf[n][4 * g + rr]);
          *(s16x4*)&lds[WT_OFF + e * 256 + ((2 * d0) ^ ((e & 7) << 4))] = p;
        }
      }
    }
    __syncthreads();
  }
}

// ---------------- row LayerNorm, in place (bf16 io, f32 gamma/beta) -----------
__global__ __launch_bounds__(256) void ln_kernel(
    unsigned short* __restrict__ io,
    const float* __restrict__ gamma,
    const float* __restrict__ beta)
{
  const int row = blockIdx.x, tid = threadIdx.x;
  const size_t base = (size_t)row * D_ + tid * 8;
  s16x8 v = *(const s16x8*)&io[base];
  float f[8], s1 = 0.f, s2 = 0.f;
  #pragma unroll
  for (int j = 0; j < 8; ++j){ f[j] = b2f(v[j]); s1 += f[j]; s2 += f[j] * f[j]; }
  #pragma unroll
  for (int off = 32; off; off >>= 1){
    s1 += __shfl_xor(s1, off);
    s2 += __shfl_xor(s2, off);
  }
  __shared__ float red[8];
  const int w = tid >> 6, l = tid & 63;
  if (l == 0){ red[w] = s1; red[4 + w] = s2; }
  __syncthreads();
  s1 = red[0] + red[1] + red[2] + red[3];
  s2 = red[4] + red[5] + red[6] + red[7];
  const float mu  = s1 * (1.0f / D_);
  const float var = s2 * (1.0f / D_) - mu * mu;
  const float rs  = rsqrtf(var + 1e-5f);
  const float4* gp = (const float4*)&gamma[tid * 8];
  const float4* bp = (const float4*)&beta[tid * 8];
  float4 g0 = gp[0], g1 = gp[1], b0 = bp[0], b1 = bp[1];
  float gg[8] = {g0.x,g0.y,g0.z,g0.w,g1.x,g1.y,g1.z,g1.w};
  float bb[8] = {b0.x,b0.y,b0.z,b0.w,b1.x,b1.y,b1.z,b1.w};
  s16x8 o;
  #pragma unroll
  for (int j = 0; j < 8; ++j)
    o[j] = f2b((f[j] - mu) * rs * gg[j] + bb[j]);
  *(s16x8*)&io[base] = o;
}

// ---------------- launch ------------------------------------------------------
extern "C" void kernel_launch(void* const* d_in, const int* in_sizes, int n_in,
                              void* d_out, int out_size, void* d_ws, size_t ws_size,
                              hipStream_t stream)
{
  const float* x     = (const float*)d_in[0];
  const float* Wk    = (const float*)d_in[1];
  const float* Wv    = (const float*)d_in[2];
  const float* Wo    = (const float*)d_in[3];
  const float* gamma = (const float*)d_in[4];
  const float* beta  = (const float*)d_in[5];
  float* out = (float*)d_out;

  // workspace layout (bytes):
  //  rope_tab 2MB | xb/ttt 64MB | k_scan 64MB | v_scan 64MB | Wkb 8MB | Wvb 8MB | Wob 8MB
  char* ws = (char*)d_ws;
  float* rope_tab        = (float*)ws;
  unsigned short* xb     = (unsigned short*)(ws + (2u << 20));
  unsigned short* k_scan = (unsigned short*)(ws + (2u << 20) + 1 * 67108864ull);
  unsigned short* v_scan = (unsigned short*)(ws + (2u << 20) + 2 * 67108864ull);
  unsigned short* Wkb    = (unsigned short*)(ws + (2u << 20) + 3 * 67108864ull);
  unsigned short* Wvb    = (unsigned short*)(ws + (2u << 20) + 3 * 67108864ull + 1 * 8388608ull);
  unsigned short* Wob    = (unsigned short*)(ws + (2u << 20) + 3 * 67108864ull + 2 * 8388608ull);
  unsigned short* ttt    = xb;  // x dead after gemm_kv

  const int nx8 = B_ * S_ * D_ / 8;        // 4,194,304
  const int nw8 = D_ * D_ / 8;             // 524,288
  cvt_kernel<<<dim3(nx8 / 256), dim3(256), 0, stream>>>(x, xb, nx8);
  cvt3_kernel<<<dim3(3 * nw8 / 256), dim3(256), 0, stream>>>(Wk, Wv, Wo, Wkb, Wvb, Wob);
  rope_tab_kernel<<<dim3(1024), dim3(256), 0, stream>>>(rope_tab);

  gemm_kv<<<dim3(4096), dim3(256), 0, stream>>>(xb, Wkb, Wvb, rope_tab, k_scan, v_scan);
  ttt_scan<<<dim3(128), dim3(256), 0, stream>>>(k_scan, v_scan, ttt);
  ln_kernel<<<dim3(B_ * S_), dim3(256), 0, stream>>>(ttt, gamma, beta);
  gemm_out<<<dim3(2048), dim3(256), 0, stream>>>(ttt, Wob, out);
}